// Round 3
// baseline (905.971 us; speedup 1.0000x reference)
//
#include <hip/hip_runtime.h>
#include <hip/hip_bf16.h>

#define EPSBN 1e-5f
#define NEG_SLOPE 0.2f

// ---- workspace layout (float offsets) ----
#define O_Y1      0            // 128*59*59*32 = 14,258,176
#define O_Y3      0            // 128*14*14*128 = 3,211,264 (after y1 dead)
#define O_Y4      3211264      // 128*6*6*256 = 1,179,648
#define O_G3      4390912      // 128*14*14 = 25,088
#define O_G1      14258176     // 128*59*59 = 445,568
#define O_Y2      14703744     // 128*29*29*64 = 6,889,472
#define O_G2      21593216     // 128*29*29 = 107,648
#define O_WK2     21700864     // 9*32*64  = 18,432
#define O_WK3     21719296     // 9*64*128 = 73,728
#define O_WK4     21793024     // 9*128*256 = 294,912
#define O_W1R     22087936     // 9*32 = 288
#define O_WADVR   22088224     // 9216
#define O_STATS   22097440     // st2[128] st3[256] st4[512] ([sc[C]; sh[C]])
#define O_PART    22098336     // max 64*211*2 = 27,008
// total < 22.16M floats = 88.7 MB

__global__ void repack_kernel(const float* __restrict__ w1,
                              const float* __restrict__ w2,
                              const float* __restrict__ w3,
                              const float* __restrict__ w4,
                              const float* __restrict__ wadv,
                              float* __restrict__ ws) {
  int idx = blockIdx.x * 256 + threadIdx.x;
  if (idx < 18432) {                       // wk2 [k][ci][co]: co=64, ci=32
    int co = idx & 63; int t = idx >> 6; int ci = t & 31; int k = t >> 5;
    ws[O_WK2 + idx] = w2[(co * 32 + ci) * 9 + k];
  } else if (idx < 92160) {                // wk3: co=128, ci=64
    int i = idx - 18432;
    int co = i & 127; int t = i >> 7; int ci = t & 63; int k = t >> 6;
    ws[O_WK3 + i] = w3[(co * 64 + ci) * 9 + k];
  } else if (idx < 387072) {               // wk4: co=256, ci=128
    int i = idx - 92160;
    int co = i & 255; int t = i >> 8; int ci = t & 127; int k = t >> 7;
    ws[O_WK4 + i] = w4[(co * 128 + ci) * 9 + k];
  } else if (idx < 387360) {               // w1r: [k][co], co=32
    int i = idx - 387072;
    int co = i & 31; int k = i >> 5;
    ws[O_W1R + i] = w1[co * 9 + k];
  } else if (idx < 396576) {               // wadv -> NHWC flatten order, prescaled
    int i = idx - 387360;
    int c = i & 255; int hw = i >> 8;      // i = hw*256 + c ; src = c*36 + hw
    ws[O_WADVR + i] = wadv[c * 36 + hw] * (1.0f / 96.0f);
  }
}

// conv1 (Cin=1) + leaky relu -> NHWC (N,59,59,32)
__global__ void conv1_kernel(const float* __restrict__ x,
                             const float* __restrict__ w1r,
                             const float* __restrict__ b1,
                             float* __restrict__ y1) {
  int idx = blockIdx.x * 256 + threadIdx.x;   // exact grid 14,258,176
  int co = idx & 31;
  int t = idx >> 5;
  int ow = t % 59; t /= 59;
  int oh = t % 59; int n = t / 59;
  const float* xb = x + (n * 120 + oh * 2) * 120 + ow * 2;
  float acc = b1[co];
#pragma unroll
  for (int kh = 0; kh < 3; ++kh)
#pragma unroll
    for (int kw = 0; kw < 3; ++kw)
      acc += xb[kh * 120 + kw] * w1r[(kh * 3 + kw) * 32 + co];
  y1[idx] = acc >= 0.0f ? acc : NEG_SLOPE * acc;
}

__global__ void avgpool_kernel(const float* __restrict__ gin, float* __restrict__ gout,
                               int HI, int HO, int total) {
  int idx = blockIdx.x * 256 + threadIdx.x;
  if (idx >= total) return;
  int ow = idx % HO; int t = idx / HO; int oh = t % HO; int n = t / HO;
  const float* gb = gin + (n * HI + oh * 2) * HI + ow * 2;
  float s = 0.0f;
#pragma unroll
  for (int kh = 0; kh < 3; ++kh)
#pragma unroll
    for (int kw = 0; kw < 3; ++kw)
      s += gb[kh * HI + kw];
  gout[idx] = s * (1.0f / 9.0f);
}

// PacConv + lrelu + fused input-BN + fused output-BN partial stats.
// lanes = pixels (PB per thread), CO_BLK output channels register-blocked.
// Weights double-buffered in LDS per tap (global->reg prefetch during compute,
// ds_write after); inner-loop weight reads are uniform-addr ds_read_b128
// broadcasts. x NHWC, wk [k][ci][co], y NHWC (pre-BN, lrelu'd).
template <int CI, int CO, int CO_BLK, int PB, int HI, int HO, bool BN_IN, int PIX, int NBLK>
__global__ __launch_bounds__(256, 3)
void pac_kernel(const float* __restrict__ x, const float* __restrict__ g,
                const float* __restrict__ wk, const float* __restrict__ b,
                const float* __restrict__ bnst,
                float* __restrict__ y, float* __restrict__ part) {
  constexpr int WTILE = CI * CO_BLK;      // floats per tap tile
  constexpr int E = WTILE / 256;          // staged floats per thread per tap
  const int tid = threadIdx.x;
  const int blk = blockIdx.x % NBLK;
  const int co0 = (blockIdx.x / NBLK) * CO_BLK;

  __shared__ float wbuf[2][WTILE];
  __shared__ float bsc[CI], bsh[CI];
  __shared__ float ps[4][2 * CO_BLK];

  if constexpr (BN_IN) {
    for (int i = tid; i < CI; i += 256) { bsc[i] = bnst[i]; bsh[i] = bnst[CI + i]; }
  }

  int p[PB]; bool valid[PB];
  float kker[PB][9];
  const float* xbase[PB];
#pragma unroll
  for (int pb = 0; pb < PB; ++pb) {
    p[pb] = blk * (256 * PB) + pb * 256 + tid;
    valid[pb] = p[pb] < PIX;
    int pc = valid[pb] ? p[pb] : 0;
    int ow = pc % HO;
    int oh = (pc / HO) % HO;
    int n  = pc / (HO * HO);
    const float* gb = g + (n * HI + oh * 2) * HI + ow * 2;
    float gc = gb[HI + 1];
#pragma unroll
    for (int kh = 0; kh < 3; ++kh)
#pragma unroll
      for (int kw = 0; kw < 3; ++kw) {
        float d = gb[kh * HI + kw] - gc;
        kker[pb][kh * 3 + kw] = __expf(-0.5f * d * d);
      }
    xbase[pb] = x + ((size_t)(n * HI + oh * 2) * HI + ow * 2) * CI;
  }

  float acc[PB][CO_BLK];
#pragma unroll
  for (int cg = 0; cg < CO_BLK / 4; ++cg) {
    float4 bv = *reinterpret_cast<const float4*>(b + co0 + cg * 4);
#pragma unroll
    for (int pb = 0; pb < PB; ++pb) {
      acc[pb][cg * 4 + 0] = bv.x; acc[pb][cg * 4 + 1] = bv.y;
      acc[pb][cg * 4 + 2] = bv.z; acc[pb][cg * 4 + 3] = bv.w;
    }
  }

  // stage tap 0
  {
    const float* wsrc = wk + co0;
#pragma unroll
    for (int e = 0; e < E; ++e) {
      int elem = e * 256 + tid;
      wbuf[0][elem] = wsrc[(elem / CO_BLK) * CO + (elem % CO_BLK)];
    }
  }

#pragma unroll 1
  for (int k = 0; k < 9; ++k) {
    __syncthreads();   // wbuf[k&1] ready; wbuf[(k+1)&1] free for overwrite

    // prefetch next tap into registers (VMEM overlaps with compute below)
    float stg[E];
    if (k < 8) {
      const float* wsrc = wk + (k + 1) * (CI * CO) + co0;
#pragma unroll
      for (int e = 0; e < E; ++e) {
        int elem = e * 256 + tid;
        stg[e] = wsrc[(elem / CO_BLK) * CO + (elem % CO_BLK)];
      }
    }

    const float* wl = wbuf[k & 1];
    const int xoff = ((k / 3) * HI + (k % 3)) * CI;
    float kk[PB];
#pragma unroll
    for (int pb = 0; pb < PB; ++pb) kk[pb] = kker[pb][k];

#pragma unroll 2
    for (int c4 = 0; c4 < CI / 4; ++c4) {
      float xq[PB][4];
#pragma unroll
      for (int pb = 0; pb < PB; ++pb) {
        float4 xv = *reinterpret_cast<const float4*>(xbase[pb] + xoff + c4 * 4);
        if constexpr (BN_IN) {
          float4 sc = *reinterpret_cast<const float4*>(&bsc[c4 * 4]);
          float4 sh = *reinterpret_cast<const float4*>(&bsh[c4 * 4]);
          xv.x = xv.x * sc.x + sh.x; xv.y = xv.y * sc.y + sh.y;
          xv.z = xv.z * sc.z + sh.z; xv.w = xv.w * sc.w + sh.w;
        }
        xq[pb][0] = xv.x * kk[pb]; xq[pb][1] = xv.y * kk[pb];
        xq[pb][2] = xv.z * kk[pb]; xq[pb][3] = xv.w * kk[pb];
      }
#pragma unroll
      for (int r = 0; r < 4; ++r) {
#pragma unroll
        for (int cg = 0; cg < CO_BLK / 4; ++cg) {
          float4 wv = *reinterpret_cast<const float4*>(&wl[(c4 * 4 + r) * CO_BLK + cg * 4]);
#pragma unroll
          for (int pb = 0; pb < PB; ++pb) {
            acc[pb][cg * 4 + 0] += xq[pb][r] * wv.x;
            acc[pb][cg * 4 + 1] += xq[pb][r] * wv.y;
            acc[pb][cg * 4 + 2] += xq[pb][r] * wv.z;
            acc[pb][cg * 4 + 3] += xq[pb][r] * wv.w;
          }
        }
      }
    }

    // commit prefetched tap to the other buffer (visible after next barrier)
    if (k < 8) {
#pragma unroll
      for (int e = 0; e < E; ++e) wbuf[(k + 1) & 1][e * 256 + tid] = stg[e];
    }
  }

  // epilogue: lrelu, store, per-channel partial (sum, sumsq)
  const int wv = tid >> 6;
  const int lane = tid & 63;
#pragma unroll
  for (int pb = 0; pb < PB; ++pb) {
#pragma unroll
    for (int j = 0; j < CO_BLK; ++j) {
      float v = acc[pb][j];
      acc[pb][j] = v >= 0.0f ? v : NEG_SLOPE * v;
    }
    if (valid[pb]) {
#pragma unroll
      for (int cg = 0; cg < CO_BLK / 4; ++cg) {
        float4 o4;
        o4.x = acc[pb][cg * 4 + 0]; o4.y = acc[pb][cg * 4 + 1];
        o4.z = acc[pb][cg * 4 + 2]; o4.w = acc[pb][cg * 4 + 3];
        *reinterpret_cast<float4*>(y + (size_t)p[pb] * CO + co0 + cg * 4) = o4;
      }
    }
  }
#pragma unroll
  for (int j = 0; j < CO_BLK; ++j) {
    float s = 0.0f, q = 0.0f;
#pragma unroll
    for (int pb = 0; pb < PB; ++pb) {
      float v = valid[pb] ? acc[pb][j] : 0.0f;
      s += v; q += v * v;
    }
#pragma unroll
    for (int off = 1; off < 64; off <<= 1) {
      s += __shfl_xor(s, off, 64);
      q += __shfl_xor(q, off, 64);
    }
    if (lane == 0) { ps[wv][j * 2 + 0] = s; ps[wv][j * 2 + 1] = q; }
  }
  __syncthreads();
  if (tid < CO_BLK) {
    float s = ps[0][tid * 2] + ps[1][tid * 2] + ps[2][tid * 2] + ps[3][tid * 2];
    float q = ps[0][tid * 2 + 1] + ps[1][tid * 2 + 1] + ps[2][tid * 2 + 1] + ps[3][tid * 2 + 1];
    part[((co0 + tid) * NBLK + blk) * 2 + 0] = s;
    part[((co0 + tid) * NBLK + blk) * 2 + 1] = q;
  }
}

// reduce partials -> st = [sc[C]; sh[C]]
template <int C>
__global__ void bnstat2_kernel(const float* __restrict__ part,
                               const float* __restrict__ gamma,
                               const float* __restrict__ beta,
                               float* __restrict__ st, float invM, int NBLK) {
  int c = blockIdx.x;
  int t = threadIdx.x;
  float s = 0.0f, q = 0.0f;
  for (int slot = t; slot < NBLK; slot += 256) {
    s += part[(c * NBLK + slot) * 2 + 0];
    q += part[(c * NBLK + slot) * 2 + 1];
  }
  __shared__ float ss[256], sq[256];
  ss[t] = s; sq[t] = q; __syncthreads();
  for (int off = 128; off > 0; off >>= 1) {
    if (t < off) { ss[t] += ss[t + off]; sq[t] += sq[t + off]; }
    __syncthreads();
  }
  if (t == 0) {
    float m = ss[0] * invM;
    float v = sq[0] * invM - m * m;
    float sc = gamma[c] * rsqrtf(v + EPSBN);
    st[c] = sc;
    st[C + c] = beta[c] - m * sc;
  }
}

// EqualLinear with fused BN4 on input
__global__ void linear_kernel(const float* __restrict__ y4, const float* __restrict__ st4,
                              const float* __restrict__ wadvr, const float* __restrict__ badv,
                              float* __restrict__ out) {
  int n = blockIdx.x, t = threadIdx.x;
  float sc = st4[t], sh = st4[256 + t];  // c = j & 255 == t for stride-256 loop
  float s = 0.0f;
  for (int j = t; j < 9216; j += 256) s += (y4[n * 9216 + j] * sc + sh) * wadvr[j];
  __shared__ float ss[256];
  ss[t] = s; __syncthreads();
  for (int off = 128; off > 0; off >>= 1) {
    if (t < off) ss[t] += ss[t + off];
    __syncthreads();
  }
  if (t == 0) out[n] = ss[0] + badv[0];
}

extern "C" void kernel_launch(void* const* d_in, const int* in_sizes, int n_in,
                              void* d_out, int out_size, void* d_ws, size_t ws_size,
                              hipStream_t stream) {
  const float* x    = (const float*)d_in[0];
  const float* gd   = (const float*)d_in[1];
  const float* w1   = (const float*)d_in[2];
  const float* b1   = (const float*)d_in[3];
  const float* w2   = (const float*)d_in[4];
  const float* b2   = (const float*)d_in[5];
  const float* w3   = (const float*)d_in[6];
  const float* b3   = (const float*)d_in[7];
  const float* w4   = (const float*)d_in[8];
  const float* b4   = (const float*)d_in[9];
  const float* bg2  = (const float*)d_in[10];
  const float* bb2  = (const float*)d_in[11];
  const float* bg3  = (const float*)d_in[12];
  const float* bb3  = (const float*)d_in[13];
  const float* bg4  = (const float*)d_in[14];
  const float* bb4  = (const float*)d_in[15];
  const float* wadv = (const float*)d_in[16];
  const float* badv = (const float*)d_in[17];
  float* out = (float*)d_out;
  float* ws  = (float*)d_ws;

  float* st2 = ws + O_STATS;        // [sc64; sh64]
  float* st3 = ws + O_STATS + 128;  // [sc128; sh128]
  float* st4 = ws + O_STATS + 384;  // [sc256; sh256]

  repack_kernel<<<1550, 256, 0, stream>>>(w1, w2, w3, w4, wadv, ws);
  conv1_kernel<<<55696, 256, 0, stream>>>(x, ws + O_W1R, b1, ws + O_Y1);
  avgpool_kernel<<<1741, 256, 0, stream>>>(gd, ws + O_G1, 120, 59, 445568);

  // pac2: CI=32 CO=64, CO_BLK=16, PB=2: 211 pixel-blocks x 4 cotiles = 844
  pac_kernel<32, 64, 16, 2, 59, 29, false, 107648, 211><<<844, 256, 0, stream>>>(
      ws + O_Y1, ws + O_G1, ws + O_WK2, b2, nullptr, ws + O_Y2, ws + O_PART);
  bnstat2_kernel<64><<<64, 256, 0, stream>>>(ws + O_PART, bg2, bb2, st2, 1.0f / 107648.0f, 211);
  avgpool_kernel<<<421, 256, 0, stream>>>(ws + O_G1, ws + O_G2, 59, 29, 107648);

  // pac3: CI=64 CO=128, CO_BLK=16, PB=2: 49 x 8 = 392
  pac_kernel<64, 128, 16, 2, 29, 14, true, 25088, 49><<<392, 256, 0, stream>>>(
      ws + O_Y2, ws + O_G2, ws + O_WK3, b3, st2, ws + O_Y3, ws + O_PART);
  bnstat2_kernel<128><<<128, 256, 0, stream>>>(ws + O_PART, bg3, bb3, st3, 1.0f / 25088.0f, 49);
  avgpool_kernel<<<98, 256, 0, stream>>>(ws + O_G2, ws + O_G3, 29, 14, 25088);

  // pac4: CI=128 CO=256, CO_BLK=16, PB=1: 18 x 16 = 288
  pac_kernel<128, 256, 16, 1, 14, 6, true, 4608, 18><<<288, 256, 0, stream>>>(
      ws + O_Y3, ws + O_G3, ws + O_WK4, b4, st3, ws + O_Y4, ws + O_PART);
  bnstat2_kernel<256><<<256, 256, 0, stream>>>(ws + O_PART, bg4, bb4, st4, 1.0f / 4608.0f, 18);

  linear_kernel<<<128, 256, 0, stream>>>(ws + O_Y4, st4, ws + O_WADVR, badv, out);
}

// Round 4
// 574.090 us; speedup vs baseline: 1.5781x; 1.5781x over previous
//
#include <hip/hip_runtime.h>
#include <hip/hip_bf16.h>

#define EPSBN 1e-5f
#define NEG_SLOPE 0.2f

// ---- workspace layout (float offsets) ----
#define O_Y1      0            // 128*59*59*32 = 14,258,176 (dead after pac2)
#define O_G1      14258176     // 128*59*59 = 445,568
#define O_Y2      14703744     // 128*29*29*64 = 6,889,472 (dead after pac3)
#define O_G2      21593216     // 128*29*29 = 107,648
#define O_WK2     21700864     // 9*32*64  = 18,432
#define O_WK3     21719296     // 9*64*128 = 73,728
#define O_WK4     21793024     // 9*128*256 = 294,912
#define O_W1R     22087936     // 9*32 = 288
#define O_WADVR   22088224     // 9216
#define O_STATS   22097440     // st2[128] st3[256] st4[512]
#define O_PART    22098336     // pac2 stats: 64*421*2 = 53,888 (ends 22,152,224)
// regions reusing dead space:
#define O_POUT3   0            // 3*3,211,264 = 9,633,792 (in dead y1)
#define O_Y3      9633792      // 3,211,264 (in dead y1)
#define O_PART3   13000000     // 128*1568*2 = 401,408 (dead y1 tail; dead before pac4)
#define O_POUT4   12845056     // 3*1,179,648 = 3,538,944 (dead y1 tail + dead g1/y2 head)
#define O_Y4      16384000     // 1,179,648 (in dead y2)
#define O_G3      17563648     // 25,088 (in dead y2)
#define O_PART4   0            // 256*576*2 = 294,912 (pout3 dead by then)

__device__ __forceinline__ void gload_lds16(const float* gsrc, float* ldst) {
  __builtin_amdgcn_global_load_lds(
      (const __attribute__((address_space(1))) unsigned int*)gsrc,
      (__attribute__((address_space(3))) unsigned int*)ldst, 16, 0, 0);
}

__global__ void repack_kernel(const float* __restrict__ w1,
                              const float* __restrict__ w2,
                              const float* __restrict__ w3,
                              const float* __restrict__ w4,
                              const float* __restrict__ wadv,
                              float* __restrict__ ws) {
  int idx = blockIdx.x * 256 + threadIdx.x;
  if (idx < 18432) {                       // wk2 [k][ci][co]: co=64, ci=32
    int co = idx & 63; int t = idx >> 6; int ci = t & 31; int k = t >> 5;
    ws[O_WK2 + idx] = w2[(co * 32 + ci) * 9 + k];
  } else if (idx < 92160) {                // wk3: co=128, ci=64
    int i = idx - 18432;
    int co = i & 127; int t = i >> 7; int ci = t & 63; int k = t >> 6;
    ws[O_WK3 + i] = w3[(co * 64 + ci) * 9 + k];
  } else if (idx < 387072) {               // wk4: co=256, ci=128
    int i = idx - 92160;
    int co = i & 255; int t = i >> 8; int ci = t & 127; int k = t >> 7;
    ws[O_WK4 + i] = w4[(co * 128 + ci) * 9 + k];
  } else if (idx < 387360) {               // w1r: [k][co], co=32
    int i = idx - 387072;
    int co = i & 31; int k = i >> 5;
    ws[O_W1R + i] = w1[co * 9 + k];
  } else if (idx < 396576) {               // wadv -> NHWC flatten order, prescaled
    int i = idx - 387360;
    int c = i & 255; int hw = i >> 8;      // src = c*36 + hw
    ws[O_WADVR + i] = wadv[c * 36 + hw] * (1.0f / 96.0f);
  }
}

// conv1 (Cin=1) + leaky relu -> NHWC (N,59,59,32)
__global__ void conv1_kernel(const float* __restrict__ x,
                             const float* __restrict__ w1r,
                             const float* __restrict__ b1,
                             float* __restrict__ y1) {
  int idx = blockIdx.x * 256 + threadIdx.x;   // exact grid 14,258,176
  int co = idx & 31;
  int t = idx >> 5;
  int ow = t % 59; t /= 59;
  int oh = t % 59; int n = t / 59;
  const float* xb = x + (n * 120 + oh * 2) * 120 + ow * 2;
  float acc = b1[co];
#pragma unroll
  for (int kh = 0; kh < 3; ++kh)
#pragma unroll
    for (int kw = 0; kw < 3; ++kw)
      acc += xb[kh * 120 + kw] * w1r[(kh * 3 + kw) * 32 + co];
  y1[idx] = acc >= 0.0f ? acc : NEG_SLOPE * acc;
}

__global__ void avgpool_kernel(const float* __restrict__ gin, float* __restrict__ gout,
                               int HI, int HO, int total) {
  int idx = blockIdx.x * 256 + threadIdx.x;
  if (idx >= total) return;
  int ow = idx % HO; int t = idx / HO; int oh = t % HO; int n = t / HO;
  const float* gb = gin + (n * HI + oh * 2) * HI + ow * 2;
  float s = 0.0f;
#pragma unroll
  for (int kh = 0; kh < 3; ++kh)
#pragma unroll
    for (int kw = 0; kw < 3; ++kw)
      s += gb[kh * HI + kw];
  gout[idx] = s * (1.0f / 9.0f);
}

// PacConv: lanes = pixels, CO_BLK=64 channels in registers, weights staged to
// LDS per tap via global_load_lds (x16), double-buffered, barrier-drained.
// FUSE: full 9 taps, bias+lrelu+store y+BN-stat partials.
// !FUSE: TAPS taps starting at kseg*TAPS, raw partial to pout[kseg].
template <int CI, int CO, int CO_BLK, int HI, int HO, bool BN_IN, int PIX,
          int NBLK, int NCOT, int TAPS, bool FUSE, int MINW>
__global__ __launch_bounds__(256, MINW)
void pac_kernel(const float* __restrict__ x, const float* __restrict__ g,
                const float* __restrict__ wk, const float* __restrict__ b,
                const float* __restrict__ bnst,
                float* __restrict__ y, float* __restrict__ part) {
  constexpr int T = CI * CO_BLK;          // floats per tap tile
  constexpr int NCHUNK = T / 1024;        // x16 issues per wave (4 waves)
  static_assert(T % 1024 == 0, "tile");
  const int tid = threadIdx.x;
  const int lane = tid & 63;
  const int wv = tid >> 6;
  const int bi = blockIdx.x;
  const int blk = bi % NBLK;
  const int cot = (bi / NBLK) % NCOT;
  const int kseg = bi / (NBLK * NCOT);
  const int co0 = cot * CO_BLK;
  const int k0 = kseg * TAPS;

  __shared__ float wbuf[2][T];
  __shared__ float bsc[CI], bsh[CI];
  __shared__ float ps[4][2 * CO_BLK];

  if constexpr (BN_IN) {
    for (int i = tid; i < CI; i += 256) { bsc[i] = bnst[i]; bsh[i] = bnst[CI + i]; }
  }

  auto stage = [&](int bb, int k) {
    const float* src = wk + k * (CI * CO) + co0;
#pragma unroll
    for (int j = 0; j < NCHUNK; ++j) {
      int chunk = j * 4 + wv;
      int e0 = chunk * 256 + lane * 4;
      int ci = e0 / CO_BLK, co = e0 % CO_BLK;
      gload_lds16(src + ci * CO + co, &wbuf[bb][e0]);
    }
  };
  stage(0, k0);

  const int p = blk * 256 + tid;
  const bool valid = FUSE ? (p < PIX) : true;
  const int pc = valid ? p : 0;
  const int ow = pc % HO;
  const int oh = (pc / HO) % HO;
  const int n  = pc / (HO * HO);

  const float* gn = g + n * (HI * HI);
  const float gc = gn[(oh * 2 + 1) * HI + (ow * 2 + 1)];
  float kker[TAPS];
#pragma unroll
  for (int kt = 0; kt < TAPS; ++kt) {
    int k = k0 + kt;
    int kh = k / 3, kw = k % 3;
    float d = gn[(oh * 2 + kh) * HI + (ow * 2 + kw)] - gc;
    kker[kt] = __expf(-0.5f * d * d);
  }

  float acc[CO_BLK];
  if constexpr (FUSE) {
#pragma unroll
    for (int cg = 0; cg < CO_BLK / 4; ++cg) {
      float4 bv = *reinterpret_cast<const float4*>(b + co0 + cg * 4);
      acc[cg * 4 + 0] = bv.x; acc[cg * 4 + 1] = bv.y;
      acc[cg * 4 + 2] = bv.z; acc[cg * 4 + 3] = bv.w;
    }
  } else {
#pragma unroll
    for (int j = 0; j < CO_BLK; ++j) acc[j] = 0.0f;
  }

#pragma unroll 1
  for (int kt = 0; kt < TAPS; ++kt) {
    __syncthreads();                       // drains staged loads for wbuf[kt&1]
    if (kt + 1 < TAPS) stage((kt + 1) & 1, k0 + kt + 1);
    const int k = k0 + kt;
    const int kh = k / 3, kw = k % 3;
    const float kk = kker[kt];
    const float* wl = wbuf[kt & 1];
    const float* xr = x + (((size_t)n * HI + (oh * 2 + kh)) * HI + (ow * 2 + kw)) * CI;
#pragma unroll 4
    for (int c4 = 0; c4 < CI / 4; ++c4) {
      float4 xv = *reinterpret_cast<const float4*>(xr + c4 * 4);
      if constexpr (BN_IN) {
        float4 sc = *reinterpret_cast<const float4*>(&bsc[c4 * 4]);
        float4 sh = *reinterpret_cast<const float4*>(&bsh[c4 * 4]);
        xv.x = xv.x * sc.x + sh.x; xv.y = xv.y * sc.y + sh.y;
        xv.z = xv.z * sc.z + sh.z; xv.w = xv.w * sc.w + sh.w;
      }
      float xa[4] = {xv.x * kk, xv.y * kk, xv.z * kk, xv.w * kk};
#pragma unroll
      for (int r = 0; r < 4; ++r) {
        const float* wrow = wl + (c4 * 4 + r) * CO_BLK;
#pragma unroll
        for (int cg = 0; cg < CO_BLK / 4; ++cg) {
          float4 w4 = *reinterpret_cast<const float4*>(wrow + cg * 4);
          acc[cg * 4 + 0] += xa[r] * w4.x;
          acc[cg * 4 + 1] += xa[r] * w4.y;
          acc[cg * 4 + 2] += xa[r] * w4.z;
          acc[cg * 4 + 3] += xa[r] * w4.w;
        }
      }
    }
  }

  if constexpr (FUSE) {
    // lrelu + store + per-channel partial (sum, sumsq)
#pragma unroll
    for (int j = 0; j < CO_BLK; ++j) {
      float v = acc[j];
      acc[j] = v >= 0.0f ? v : NEG_SLOPE * v;
    }
    if (valid) {
#pragma unroll
      for (int cg = 0; cg < CO_BLK / 4; ++cg) {
        float4 o4;
        o4.x = acc[cg * 4 + 0]; o4.y = acc[cg * 4 + 1];
        o4.z = acc[cg * 4 + 2]; o4.w = acc[cg * 4 + 3];
        *reinterpret_cast<float4*>(y + (size_t)p * CO + co0 + cg * 4) = o4;
      }
    }
#pragma unroll
    for (int j = 0; j < CO_BLK; ++j) {
      float s = valid ? acc[j] : 0.0f;
      float q = s * s;
#pragma unroll
      for (int off = 1; off < 64; off <<= 1) {
        s += __shfl_xor(s, off, 64);
        q += __shfl_xor(q, off, 64);
      }
      if (lane == 0) { ps[wv][j * 2 + 0] = s; ps[wv][j * 2 + 1] = q; }
    }
    __syncthreads();
    if (tid < CO_BLK) {
      float s = ps[0][tid * 2] + ps[1][tid * 2] + ps[2][tid * 2] + ps[3][tid * 2];
      float q = ps[0][tid * 2 + 1] + ps[1][tid * 2 + 1] + ps[2][tid * 2 + 1] + ps[3][tid * 2 + 1];
      part[((co0 + tid) * NBLK + blk) * 2 + 0] = s;
      part[((co0 + tid) * NBLK + blk) * 2 + 1] = q;
    }
  } else {
    float* pd = y + ((size_t)kseg * PIX + p) * CO + co0;
#pragma unroll
    for (int cg = 0; cg < CO_BLK / 4; ++cg) {
      float4 o4;
      o4.x = acc[cg * 4 + 0]; o4.y = acc[cg * 4 + 1];
      o4.z = acc[cg * 4 + 2]; o4.w = acc[cg * 4 + 3];
      *reinterpret_cast<float4*>(pd + cg * 4) = o4;
    }
  }
}

// sum 3 K-partials + bias -> lrelu -> y, plus per-channel BN-stat partials
template <int CO, int EPT>
__global__ void combine_kernel(const float* __restrict__ pout, int pixco,
                               const float* __restrict__ b,
                               float* __restrict__ y, float* __restrict__ part, int NB) {
  const int tid = threadIdx.x, blk = blockIdx.x;
  const int base = blk * (256 * EPT);
  const int co = tid & (CO - 1);
  const float bias = b[co];
  float s = 0.0f, q = 0.0f;
#pragma unroll
  for (int i = 0; i < EPT; ++i) {
    int e = base + i * 256 + tid;
    float v = pout[e] + pout[pixco + e] + pout[2 * pixco + e] + bias;
    v = v >= 0.0f ? v : NEG_SLOPE * v;
    y[e] = v;
    s += v; q += v * v;
  }
  if constexpr (CO < 256) {
    __shared__ float sm[2][256];
    sm[0][tid] = s; sm[1][tid] = q;
    __syncthreads();
    if (tid < CO) {
      for (int o = CO; o < 256; o += CO) { s += sm[0][tid + o]; q += sm[1][tid + o]; }
      part[(co * NB + blk) * 2 + 0] = s;
      part[(co * NB + blk) * 2 + 1] = q;
    }
  } else {
    part[(co * NB + blk) * 2 + 0] = s;
    part[(co * NB + blk) * 2 + 1] = q;
  }
}

// reduce partials -> st = [sc[C]; sh[C]]
template <int C>
__global__ void bnstat2_kernel(const float* __restrict__ part,
                               const float* __restrict__ gamma,
                               const float* __restrict__ beta,
                               float* __restrict__ st, float invM, int NBLK) {
  int c = blockIdx.x;
  int t = threadIdx.x;
  float s = 0.0f, q = 0.0f;
  for (int slot = t; slot < NBLK; slot += 256) {
    s += part[(c * NBLK + slot) * 2 + 0];
    q += part[(c * NBLK + slot) * 2 + 1];
  }
  __shared__ float ss[256], sq[256];
  ss[t] = s; sq[t] = q; __syncthreads();
  for (int off = 128; off > 0; off >>= 1) {
    if (t < off) { ss[t] += ss[t + off]; sq[t] += sq[t + off]; }
    __syncthreads();
  }
  if (t == 0) {
    float m = ss[0] * invM;
    float v = sq[0] * invM - m * m;
    float sc = gamma[c] * rsqrtf(v + EPSBN);
    st[c] = sc;
    st[C + c] = beta[c] - m * sc;
  }
}

// EqualLinear with fused BN4 on input
__global__ void linear_kernel(const float* __restrict__ y4, const float* __restrict__ st4,
                              const float* __restrict__ wadvr, const float* __restrict__ badv,
                              float* __restrict__ out) {
  int n = blockIdx.x, t = threadIdx.x;
  float sc = st4[t], sh = st4[256 + t];
  float s = 0.0f;
  for (int j = t; j < 9216; j += 256) s += (y4[n * 9216 + j] * sc + sh) * wadvr[j];
  __shared__ float ss[256];
  ss[t] = s; __syncthreads();
  for (int off = 128; off > 0; off >>= 1) {
    if (t < off) ss[t] += ss[t + off];
    __syncthreads();
  }
  if (t == 0) out[n] = ss[0] + badv[0];
}

extern "C" void kernel_launch(void* const* d_in, const int* in_sizes, int n_in,
                              void* d_out, int out_size, void* d_ws, size_t ws_size,
                              hipStream_t stream) {
  const float* x    = (const float*)d_in[0];
  const float* gd   = (const float*)d_in[1];
  const float* w1   = (const float*)d_in[2];
  const float* b1   = (const float*)d_in[3];
  const float* w2   = (const float*)d_in[4];
  const float* b2   = (const float*)d_in[5];
  const float* w3   = (const float*)d_in[6];
  const float* b3   = (const float*)d_in[7];
  const float* w4   = (const float*)d_in[8];
  const float* b4   = (const float*)d_in[9];
  const float* bg2  = (const float*)d_in[10];
  const float* bb2  = (const float*)d_in[11];
  const float* bg3  = (const float*)d_in[12];
  const float* bb3  = (const float*)d_in[13];
  const float* bg4  = (const float*)d_in[14];
  const float* bb4  = (const float*)d_in[15];
  const float* wadv = (const float*)d_in[16];
  const float* badv = (const float*)d_in[17];
  float* out = (float*)d_out;
  float* ws  = (float*)d_ws;

  float* st2 = ws + O_STATS;        // [sc64; sh64]
  float* st3 = ws + O_STATS + 128;  // [sc128; sh128]
  float* st4 = ws + O_STATS + 384;  // [sc256; sh256]

  repack_kernel<<<1550, 256, 0, stream>>>(w1, w2, w3, w4, wadv, ws);
  conv1_kernel<<<55696, 256, 0, stream>>>(x, ws + O_W1R, b1, ws + O_Y1);
  avgpool_kernel<<<1741, 256, 0, stream>>>(gd, ws + O_G1, 120, 59, 445568);

  // pac2: CI=32 CO=64 CO_BLK=64, fused, 421 blocks
  pac_kernel<32, 64, 64, 59, 29, false, 107648, 421, 1, 9, true, 2>
      <<<421, 256, 0, stream>>>(ws + O_Y1, ws + O_G1, ws + O_WK2, b2, nullptr,
                                ws + O_Y2, ws + O_PART);
  bnstat2_kernel<64><<<64, 256, 0, stream>>>(ws + O_PART, bg2, bb2, st2, 1.0f / 107648.0f, 421);
  avgpool_kernel<<<421, 256, 0, stream>>>(ws + O_G1, ws + O_G2, 59, 29, 107648);

  // pac3: CI=64 CO=128 CO_BLK=64, K-split 3: 98 x 2 x 3 = 588 blocks
  pac_kernel<64, 128, 64, 29, 14, true, 25088, 98, 2, 3, false, 2>
      <<<588, 256, 0, stream>>>(ws + O_Y2, ws + O_G2, ws + O_WK3, nullptr, st2,
                                ws + O_POUT3, nullptr);
  combine_kernel<128, 8><<<1568, 256, 0, stream>>>(ws + O_POUT3, 3211264, b3,
                                                   ws + O_Y3, ws + O_PART3, 1568);
  bnstat2_kernel<128><<<128, 256, 0, stream>>>(ws + O_PART3, bg3, bb3, st3, 1.0f / 25088.0f, 1568);
  avgpool_kernel<<<98, 256, 0, stream>>>(ws + O_G2, ws + O_G3, 29, 14, 25088);

  // pac4: CI=128 CO=256 CO_BLK=64, K-split 3: 18 x 4 x 3 = 216 blocks
  pac_kernel<128, 256, 64, 14, 6, true, 4608, 18, 4, 3, false, 1>
      <<<216, 256, 0, stream>>>(ws + O_Y3, ws + O_G3, ws + O_WK4, nullptr, st3,
                                ws + O_POUT4, nullptr);
  combine_kernel<256, 8><<<576, 256, 0, stream>>>(ws + O_POUT4, 1179648, b4,
                                                  ws + O_Y4, ws + O_PART4, 576);
  bnstat2_kernel<256><<<256, 256, 0, stream>>>(ws + O_PART4, bg4, bb4, st4, 1.0f / 4608.0f, 576);

  linear_kernel<<<128, 256, 0, stream>>>(ws + O_Y4, st4, ws + O_WADVR, badv, out);
}

// Round 6
// 157.347 us; speedup vs baseline: 5.7578x; 3.6486x over previous
//
#include <hip/hip_runtime.h>
#include <hip/hip_bf16.h>

#define EPSBN 1e-5f
#define NEG_SLOPE 0.2f

using f32x4  = __attribute__((ext_vector_type(4))) float;
using bf16x8 = __attribute__((ext_vector_type(8))) short;

// ---- workspace layout (float offsets) ----
#define O_Y1      0            // 128*59*59*32 = 14,258,176 (dead after pac2)
#define O_G1      14258176     // 445,568
#define O_Y2      14703744     // 6,889,472 (dead after pac3)
#define O_G2      21593216     // 107,648
#define O_WKB2    21700864     // 18,432 shorts = 9,216 floats
#define O_WKB3    21710080     // 73,728 shorts = 36,864 floats
#define O_WKB4    21746944     // 294,912 shorts = 147,456 floats
#define O_W1R     21894400     // 288
#define O_WADVR   21894688     // 9,216
#define O_STATS   21903904     // 896
#define O_PART    21904800     // max 64*841*2 = 107,648
// reuse of dead y1 region:
#define O_Y3      0            // 3,211,264
#define O_Y4      3211264      // 1,179,648
#define O_G3      4390912      // 25,088

__device__ __forceinline__ unsigned short f2bf(float f) {
  union { float f; unsigned int u; } v; v.f = f;
  unsigned int u = v.u + 0x7FFF + ((v.u >> 16) & 1);   // RN-even
  return (unsigned short)(u >> 16);
}

__global__ void repack_kernel(const float* __restrict__ w1,
                              const float* __restrict__ w2,
                              const float* __restrict__ w3,
                              const float* __restrict__ w4,
                              const float* __restrict__ wadv,
                              float* __restrict__ ws) {
  int idx = blockIdx.x * 256 + threadIdx.x;
  if (idx < 18432) {                       // wkb2: [s=tap][co][k] bf16, CI=32
    int kk = idx & 31; int t = idx >> 5; int co = t & 63; int tap = t >> 6;
    ((unsigned short*)(ws + O_WKB2))[idx] = f2bf(w2[(co * 32 + kk) * 9 + tap]);
  } else if (idx < 92160) {                // wkb3: CI=64, KC=2, CO=128
    int i = idx - 18432;
    int kk = i & 31; int t = i >> 5; int co = t & 127; int t3 = t >> 7;
    int kc = t3 & 1; int tap = t3 >> 1;
    ((unsigned short*)(ws + O_WKB3))[i] = f2bf(w3[(co * 64 + kc * 32 + kk) * 9 + tap]);
  } else if (idx < 387072) {               // wkb4: CI=128, KC=4, CO=256
    int i = idx - 92160;
    int kk = i & 31; int t = i >> 5; int co = t & 255; int t3 = t >> 8;
    int kc = t3 & 3; int tap = t3 >> 2;
    ((unsigned short*)(ws + O_WKB4))[i] = f2bf(w4[(co * 128 + kc * 32 + kk) * 9 + tap]);
  } else if (idx < 387360) {               // w1r: [k][co] f32
    int i = idx - 387072;
    int co = i & 31; int k = i >> 5;
    ws[O_W1R + i] = w1[co * 9 + k];
  } else if (idx < 396576) {               // wadv -> NHWC flatten order, prescaled
    int i = idx - 387360;
    int c = i & 255; int hw = i >> 8;
    ws[O_WADVR + i] = wadv[c * 36 + hw] * (1.0f / 96.0f);
  }
}

// conv1 (Cin=1) + lrelu -> NHWC (N,59,59,32). block = (n, oh); x rows in LDS.
__global__ __launch_bounds__(256) void conv1_kernel(const float* __restrict__ x,
                                                    const float* __restrict__ w1r,
                                                    const float* __restrict__ b1,
                                                    float* __restrict__ y1) {
  const int bi = blockIdx.x;
  const int n = bi / 59, oh = bi % 59;
  const int tid = threadIdx.x;
  __shared__ float xs[360];
  __shared__ float wsm[320];
  for (int i = tid; i < 320; i += 256)           // FIX: strided (was if(tid<288)
    wsm[i] = (i < 288) ? w1r[i] : b1[i - 288];   //      which starved 256..319)
  {
    const float* src = x + ((size_t)n * 120 + oh * 2) * 120;
    for (int i = tid; i < 360; i += 256) xs[i] = src[i];
  }
  __syncthreads();
  const int co = tid & 31;
  const int ow0 = (tid >> 5) * 8;
  float w[9];
#pragma unroll
  for (int k = 0; k < 9; ++k) w[k] = wsm[k * 32 + co];
  const float bias = wsm[288 + co];
  float* yb = y1 + (size_t)(n * 59 + oh) * 59 * 32;
#pragma unroll
  for (int j = 0; j < 8; ++j) {
    int ow = ow0 + j;
    if (ow < 59) {
      float acc = bias;
#pragma unroll
      for (int kh = 0; kh < 3; ++kh)
#pragma unroll
        for (int kw = 0; kw < 3; ++kw)
          acc += xs[kh * 120 + ow * 2 + kw] * w[kh * 3 + kw];
      yb[ow * 32 + co] = acc >= 0.0f ? acc : NEG_SLOPE * acc;
    }
  }
}

__global__ void avgpool_kernel(const float* __restrict__ gin, float* __restrict__ gout,
                               int HI, int HO, int total) {
  int idx = blockIdx.x * 256 + threadIdx.x;
  if (idx >= total) return;
  int ow = idx % HO; int t = idx / HO; int oh = t % HO; int n = t / HO;
  const float* gb = gin + (n * HI + oh * 2) * HI + ow * 2;
  float s = 0.0f;
#pragma unroll
  for (int kh = 0; kh < 3; ++kh)
#pragma unroll
    for (int kw = 0; kw < 3; ++kw)
      s += gb[kh * HI + kw];
  gout[idx] = s * (1.0f / 9.0f);
}

// MFMA PacConv + fused input-BN + lrelu + BN-stat partials.
// Per K-step (tap,kc): A=[MBLK px][32] bf16 = x*bn*ker; B=[CO][32] bf16 weights.
// Both LDS double-buffered (pad 8 shorts/row), T14 split staging.
// Waves: wave w=(wm,wn) owns 32px x 64co via 2x4 tiles of mfma 16x16x32 bf16.
template <int CI, int CO, int HI, int HO, int MBLK, int NWM, int NWN,
          bool BN_IN, int NBLK, int MINW>
__global__ __launch_bounds__(256, MINW)
void pac_kernel(const float* __restrict__ x, const float* __restrict__ g,
                const float* __restrict__ wkb_f, const float* __restrict__ b,
                const float* __restrict__ bnst,
                float* __restrict__ y, float* __restrict__ part) {
  constexpr int KC  = CI / 32;
  constexpr int S   = 9 * KC;
  constexpr int TPP = 256 / MBLK;      // threads per pixel (A staging)
  constexpr int CPT = 32 / TPP;        // channels per thread (A staging)
  constexpr int NU4 = CO / 64;         // uint4s per thread (B staging)
  constexpr int BSZ = BN_IN ? CI : 1;
  const unsigned short* wkb = (const unsigned short*)wkb_f;

  __shared__ unsigned short Ash[2][MBLK * 40];
  __shared__ unsigned short Bsh[2][CO * 40];
  __shared__ float kkl[MBLK * 9];
  __shared__ int   xofl[MBLK];
  __shared__ float bscl[BSZ], bshl[BSZ];
  __shared__ float ps[NWM][CO * 2];

  const int tid  = threadIdx.x;
  const int lane = tid & 63;
  const int wv   = tid >> 6;
  const int wm   = wv / NWN, wn = wv % NWN;
  const int blk  = blockIdx.x;

  if constexpr (BN_IN) {
    for (int i = tid; i < CI; i += 256) { bscl[i] = bnst[i]; bshl[i] = bnst[CI + i]; }
  }
  if (tid < MBLK) {
    int p = blk * MBLK + tid;
    int ow = p % HO, oh = (p / HO) % HO, n = p / (HO * HO);
    const float* gn = g + n * (HI * HI);
    float gc = gn[(oh * 2 + 1) * HI + ow * 2 + 1];
#pragma unroll
    for (int kh = 0; kh < 3; ++kh)
#pragma unroll
      for (int kw = 0; kw < 3; ++kw) {
        float d = gn[(oh * 2 + kh) * HI + ow * 2 + kw] - gc;
        kkl[tid * 9 + kh * 3 + kw] = __expf(-0.5f * d * d);
      }
    xofl[tid] = ((n * HI + oh * 2) * HI + ow * 2) * CI;
  }
  __syncthreads();

  const int app = tid / TPP;              // A: pixel this thread stages
  const int acs = (tid % TPP) * CPT;      // A: channel start
  const int bs0 = tid * NU4 * 8;          // B: short start
  const int brow = bs0 / 32, bco = bs0 % 32;

  float areg[CPT];
  uint4 breg[NU4];

  auto loadA = [&](int s) {
    int tap = s / KC, kc = s % KC;
    const float* src = x + xofl[app] + ((tap / 3) * HI + (tap % 3)) * CI + kc * 32 + acs;
#pragma unroll
    for (int j = 0; j < CPT / 4; ++j)
      *(float4*)&areg[j * 4] = *(const float4*)&src[j * 4];
  };
  auto loadB = [&](int s) {
    const uint4* src = (const uint4*)(wkb + (size_t)s * (CO * 32));
#pragma unroll
    for (int j = 0; j < NU4; ++j) breg[j] = src[tid * NU4 + j];
  };
  auto writeA = [&](int s, int bb) {
    int tap = s / KC, kc = s % KC;
    float kk = kkl[app * 9 + tap];
    unsigned int u[CPT / 2];
#pragma unroll
    for (int j = 0; j < CPT / 2; ++j) {
      float f0 = areg[2 * j], f1 = areg[2 * j + 1];
      if constexpr (BN_IN) {
        int c = kc * 32 + acs + 2 * j;
        f0 = f0 * bscl[c] + bshl[c];
        f1 = f1 * bscl[c + 1] + bshl[c + 1];
      }
      f0 *= kk; f1 *= kk;
      u[j] = (unsigned int)f2bf(f0) | ((unsigned int)f2bf(f1) << 16);
    }
    unsigned int* dst = (unsigned int*)&Ash[bb][app * 40 + acs];
#pragma unroll
    for (int j = 0; j < CPT / 2; ++j) dst[j] = u[j];
  };
  auto writeB = [&](int bb) {
    uint4* dst = (uint4*)&Bsh[bb][brow * 40 + bco];
#pragma unroll
    for (int j = 0; j < NU4; ++j) dst[j] = breg[j];
  };

  f32x4 acc[2][4];
#pragma unroll
  for (int nt = 0; nt < 4; ++nt) {
    float bv = b[wn * 64 + nt * 16 + (lane & 15)];
#pragma unroll
    for (int mt = 0; mt < 2; ++mt) acc[mt][nt] = (f32x4){bv, bv, bv, bv};
  }

  // prologue: stage step 0 fully
  loadA(0); loadB(0);
  writeA(0, 0); writeB(0);

  const int mr = wm * 32 + (lane & 15);
  const int g8 = (lane >> 4) * 8;

#pragma unroll 1
  for (int s = 0; s < S; ++s) {
    __syncthreads();                      // buf[s&1] ready
    if (s + 1 < S) { loadA(s + 1); loadB(s + 1); }   // issue early (T14)
    const unsigned short* Ab = Ash[s & 1];
    const unsigned short* Bb = Bsh[s & 1];
    bf16x8 af[2], bfv[4];
#pragma unroll
    for (int mt = 0; mt < 2; ++mt)
      af[mt] = *(const bf16x8*)&Ab[(mr + mt * 16) * 40 + g8];
#pragma unroll
    for (int nt = 0; nt < 4; ++nt)
      bfv[nt] = *(const bf16x8*)&Bb[(wn * 64 + nt * 16 + (lane & 15)) * 40 + g8];
#pragma unroll
    for (int mt = 0; mt < 2; ++mt)
#pragma unroll
      for (int nt = 0; nt < 4; ++nt)
        acc[mt][nt] = __builtin_amdgcn_mfma_f32_16x16x32_bf16(af[mt], bfv[nt], acc[mt][nt], 0, 0, 0);
    if (s + 1 < S) { writeA(s + 1, (s + 1) & 1); writeB((s + 1) & 1); }  // write late
  }

  // epilogue: lrelu + store + per-channel (sum, sumsq) partials
#pragma unroll
  for (int nt = 0; nt < 4; ++nt) {
    const int co = wn * 64 + nt * 16 + (lane & 15);
    float s = 0.0f, q = 0.0f;
#pragma unroll
    for (int mt = 0; mt < 2; ++mt)
#pragma unroll
      for (int r = 0; r < 4; ++r) {
        float v = acc[mt][nt][r];
        v = v >= 0.0f ? v : NEG_SLOPE * v;
        int p = blk * MBLK + wm * 32 + mt * 16 + ((lane >> 4) << 2) + r;
        y[(size_t)p * CO + co] = v;
        s += v; q += v * v;
      }
    s += __shfl_xor(s, 16, 64); q += __shfl_xor(q, 16, 64);
    s += __shfl_xor(s, 32, 64); q += __shfl_xor(q, 32, 64);
    if (lane < 16) { ps[wm][co * 2 + 0] = s; ps[wm][co * 2 + 1] = q; }
  }
  __syncthreads();
  if (tid < CO) {
    float s = 0.0f, q = 0.0f;
#pragma unroll
    for (int wmx = 0; wmx < NWM; ++wmx) { s += ps[wmx][tid * 2]; q += ps[wmx][tid * 2 + 1]; }
    part[(tid * NBLK + blk) * 2 + 0] = s;
    part[(tid * NBLK + blk) * 2 + 1] = q;
  }
}

// reduce partials -> st = [sc[C]; sh[C]]
template <int C>
__global__ void bnstat2_kernel(const float* __restrict__ part,
                               const float* __restrict__ gamma,
                               const float* __restrict__ beta,
                               float* __restrict__ st, float invM, int NBLK) {
  int c = blockIdx.x;
  int t = threadIdx.x;
  float s = 0.0f, q = 0.0f;
  for (int slot = t; slot < NBLK; slot += 256) {
    s += part[(c * NBLK + slot) * 2 + 0];
    q += part[(c * NBLK + slot) * 2 + 1];
  }
  __shared__ float ss[256], sq[256];
  ss[t] = s; sq[t] = q; __syncthreads();
  for (int off = 128; off > 0; off >>= 1) {
    if (t < off) { ss[t] += ss[t + off]; sq[t] += sq[t + off]; }
    __syncthreads();
  }
  if (t == 0) {
    float m = ss[0] * invM;
    float v = sq[0] * invM - m * m;
    float sc = gamma[c] * rsqrtf(v + EPSBN);
    st[c] = sc;
    st[C + c] = beta[c] - m * sc;
  }
}

// EqualLinear with fused BN4 on input
__global__ void linear_kernel(const float* __restrict__ y4, const float* __restrict__ st4,
                              const float* __restrict__ wadvr, const float* __restrict__ badv,
                              float* __restrict__ out) {
  int n = blockIdx.x, t = threadIdx.x;
  float sc = st4[t], sh = st4[256 + t];
  float s = 0.0f;
  for (int j = t; j < 9216; j += 256) s += (y4[n * 9216 + j] * sc + sh) * wadvr[j];
  __shared__ float ss[256];
  ss[t] = s; __syncthreads();
  for (int off = 128; off > 0; off >>= 1) {
    if (t < off) ss[t] += ss[t + off];
    __syncthreads();
  }
  if (t == 0) out[n] = ss[0] + badv[0];
}

extern "C" void kernel_launch(void* const* d_in, const int* in_sizes, int n_in,
                              void* d_out, int out_size, void* d_ws, size_t ws_size,
                              hipStream_t stream) {
  const float* x    = (const float*)d_in[0];
  const float* gd   = (const float*)d_in[1];
  const float* w1   = (const float*)d_in[2];
  const float* b1   = (const float*)d_in[3];
  const float* w2   = (const float*)d_in[4];
  const float* b2   = (const float*)d_in[5];
  const float* w3   = (const float*)d_in[6];
  const float* b3   = (const float*)d_in[7];
  const float* w4   = (const float*)d_in[8];
  const float* b4   = (const float*)d_in[9];
  const float* bg2  = (const float*)d_in[10];
  const float* bb2  = (const float*)d_in[11];
  const float* bg3  = (const float*)d_in[12];
  const float* bb3  = (const float*)d_in[13];
  const float* bg4  = (const float*)d_in[14];
  const float* bb4  = (const float*)d_in[15];
  const float* wadv = (const float*)d_in[16];
  const float* badv = (const float*)d_in[17];
  float* out = (float*)d_out;
  float* ws  = (float*)d_ws;

  float* st2 = ws + O_STATS;        // [sc64; sh64]
  float* st3 = ws + O_STATS + 128;  // [sc128; sh128]
  float* st4 = ws + O_STATS + 384;  // [sc256; sh256]

  repack_kernel<<<1550, 256, 0, stream>>>(w1, w2, w3, w4, wadv, ws);
  conv1_kernel<<<7552, 256, 0, stream>>>(x, ws + O_W1R, b1, ws + O_Y1);
  avgpool_kernel<<<1741, 256, 0, stream>>>(gd, ws + O_G1, 120, 59, 445568);

  // pac2: CI=32 CO=64, MBLK=128, waves 4x1 -> 841 blocks
  pac_kernel<32, 64, 59, 29, 128, 4, 1, false, 841, 3>
      <<<841, 256, 0, stream>>>(ws + O_Y1, ws + O_G1, ws + O_WKB2, b2, nullptr,
                                ws + O_Y2, ws + O_PART);
  bnstat2_kernel<64><<<64, 256, 0, stream>>>(ws + O_PART, bg2, bb2, st2, 1.0f / 107648.0f, 841);
  avgpool_kernel<<<421, 256, 0, stream>>>(ws + O_G1, ws + O_G2, 59, 29, 107648);

  // pac3: CI=64 CO=128, MBLK=64, waves 2x2 -> 392 blocks
  pac_kernel<64, 128, 29, 14, 64, 2, 2, true, 392, 3>
      <<<392, 256, 0, stream>>>(ws + O_Y2, ws + O_G2, ws + O_WKB3, b3, st2,
                                ws + O_Y3, ws + O_PART);
  bnstat2_kernel<128><<<128, 256, 0, stream>>>(ws + O_PART, bg3, bb3, st3, 1.0f / 25088.0f, 392);
  avgpool_kernel<<<98, 256, 0, stream>>>(ws + O_G2, ws + O_G3, 29, 14, 25088);

  // pac4: CI=128 CO=256, MBLK=32, waves 1x4 -> 144 blocks
  pac_kernel<128, 256, 14, 6, 32, 1, 4, true, 144, 2>
      <<<144, 256, 0, stream>>>(ws + O_Y3, ws + O_G3, ws + O_WKB4, b4, st3,
                                ws + O_Y4, ws + O_PART);
  bnstat2_kernel<256><<<256, 256, 0, stream>>>(ws + O_PART, bg4, bb4, st4, 1.0f / 4608.0f, 144);

  linear_kernel<<<128, 256, 0, stream>>>(ws + O_Y4, st4, ws + O_WADVR, badv, out);
}

// Round 7
// 142.568 us; speedup vs baseline: 6.3547x; 1.1037x over previous
//
#include <hip/hip_runtime.h>
#include <hip/hip_bf16.h>

#define EPSBN 1e-5f
#define NEG_SLOPE 0.2f

using f32x4  = __attribute__((ext_vector_type(4))) float;
using bf16x8 = __attribute__((ext_vector_type(8))) short;

// ---- workspace layout (float offsets) ----
#define O_Y1      0            // 128*59*59*32 = 14,258,176 (dead after pac2)
#define O_G1      14258176     // 445,568
#define O_Y2      14703744     // 6,889,472 (dead after pac3)
#define O_G2      21593216     // 107,648
#define O_WKB2    21700864     // 18,432 shorts = 9,216 floats
#define O_WKB3    21710080     // 73,728 shorts = 36,864 floats
#define O_WKB4    21746944     // 294,912 shorts = 147,456 floats
#define O_W1R     21894400     // 288
#define O_WADVR   21894688     // 9,216
#define O_STATS   21903904     // 896
#define O_PART    21904800     // pac2: 64*841*2=107,648 / pac3: 128*392*2
// reuse of dead y1 region:
#define O_Y3      0            // 3,211,264
#define O_Y4      3211264      // 1,179,648
#define O_G3      4390912      // 25,088
// reuse of dead y2 region (after pac3):
#define O_POUT4   14703744     // 3*1,179,648 = 3,538,944
#define O_PART4   18242688     // 256*576*2 = 294,912

__device__ __forceinline__ unsigned short f2bf(float f) {
  union { float f; unsigned int u; } v; v.f = f;
  unsigned int u = v.u + 0x7FFF + ((v.u >> 16) & 1);   // RN-even
  return (unsigned short)(u >> 16);
}

__global__ void repack_kernel(const float* __restrict__ w1,
                              const float* __restrict__ w2,
                              const float* __restrict__ w3,
                              const float* __restrict__ w4,
                              const float* __restrict__ wadv,
                              float* __restrict__ ws) {
  int idx = blockIdx.x * 256 + threadIdx.x;
  if (idx < 18432) {                       // wkb2: [s=tap][co][k] bf16, CI=32
    int kk = idx & 31; int t = idx >> 5; int co = t & 63; int tap = t >> 6;
    ((unsigned short*)(ws + O_WKB2))[idx] = f2bf(w2[(co * 32 + kk) * 9 + tap]);
  } else if (idx < 92160) {                // wkb3: CI=64, KC=2, CO=128
    int i = idx - 18432;
    int kk = i & 31; int t = i >> 5; int co = t & 127; int t3 = t >> 7;
    int kc = t3 & 1; int tap = t3 >> 1;
    ((unsigned short*)(ws + O_WKB3))[i] = f2bf(w3[(co * 64 + kc * 32 + kk) * 9 + tap]);
  } else if (idx < 387072) {               // wkb4: CI=128, KC=4, CO=256
    int i = idx - 92160;
    int kk = i & 31; int t = i >> 5; int co = t & 255; int t3 = t >> 8;
    int kc = t3 & 3; int tap = t3 >> 2;
    ((unsigned short*)(ws + O_WKB4))[i] = f2bf(w4[(co * 128 + kc * 32 + kk) * 9 + tap]);
  } else if (idx < 387360) {               // w1r: [k][co] f32
    int i = idx - 387072;
    int co = i & 31; int k = i >> 5;
    ws[O_W1R + i] = w1[co * 9 + k];
  } else if (idx < 396576) {               // wadv -> NHWC flatten order, prescaled
    int i = idx - 387360;
    int c = i & 255; int hw = i >> 8;
    ws[O_WADVR + i] = wadv[c * 36 + hw] * (1.0f / 96.0f);
  }
}

// conv1 (Cin=1) + lrelu -> NHWC (N,59,59,32). block = (n, oh); x rows in LDS.
__global__ __launch_bounds__(256) void conv1_kernel(const float* __restrict__ x,
                                                    const float* __restrict__ w1r,
                                                    const float* __restrict__ b1,
                                                    float* __restrict__ y1) {
  const int bi = blockIdx.x;
  const int n = bi / 59, oh = bi % 59;
  const int tid = threadIdx.x;
  __shared__ float xs[360];
  __shared__ float wsm[320];
  for (int i = tid; i < 320; i += 256)
    wsm[i] = (i < 288) ? w1r[i] : b1[i - 288];
  {
    const float* src = x + ((size_t)n * 120 + oh * 2) * 120;
    for (int i = tid; i < 360; i += 256) xs[i] = src[i];
  }
  __syncthreads();
  const int co = tid & 31;
  const int ow0 = (tid >> 5) * 8;
  float w[9];
#pragma unroll
  for (int k = 0; k < 9; ++k) w[k] = wsm[k * 32 + co];
  const float bias = wsm[288 + co];
  float* yb = y1 + (size_t)(n * 59 + oh) * 59 * 32;
#pragma unroll
  for (int j = 0; j < 8; ++j) {
    int ow = ow0 + j;
    if (ow < 59) {
      float acc = bias;
#pragma unroll
      for (int kh = 0; kh < 3; ++kh)
#pragma unroll
        for (int kw = 0; kw < 3; ++kw)
          acc += xs[kh * 120 + ow * 2 + kw] * w[kh * 3 + kw];
      yb[ow * 32 + co] = acc >= 0.0f ? acc : NEG_SLOPE * acc;
    }
  }
}

__global__ void avgpool_kernel(const float* __restrict__ gin, float* __restrict__ gout,
                               int HI, int HO, int total) {
  int idx = blockIdx.x * 256 + threadIdx.x;
  if (idx >= total) return;
  int ow = idx % HO; int t = idx / HO; int oh = t % HO; int n = t / HO;
  const float* gb = gin + (n * HI + oh * 2) * HI + ow * 2;
  float s = 0.0f;
#pragma unroll
  for (int kh = 0; kh < 3; ++kh)
#pragma unroll
    for (int kw = 0; kw < 3; ++kw)
      s += gb[kh * HI + kw];
  gout[idx] = s * (1.0f / 9.0f);
}

// Barrier-free MFMA PacConv. Each lane builds its own A fragment straight from
// global x (8 consecutive channels of one pixel: BN -> *ker -> bf16) and loads
// its B fragment straight from wkb (layout [s][co][k] == fragment order; dense
// coalesced 1KB per wave-load). No LDS staging, no K-loop barriers; the S-step
// loop is fully unrolled so the compiler software-pipelines the loads.
// FUSE: bias+lrelu+store y+BN-stat partials. !FUSE: raw partial to pout[kseg].
template <int CI, int CO, int HI, int HO, int NWM, int NWN, bool BN_IN,
          bool FUSE, int SSEG, int NBLK, int MINW>
__global__ __launch_bounds__(256, MINW)
void pac_kernel(const float* __restrict__ x, const float* __restrict__ g,
                const float* __restrict__ wkb_f, const float* __restrict__ b,
                const float* __restrict__ bnst,
                float* __restrict__ y, float* __restrict__ part) {
  constexpr int KC   = CI / 32;
  constexpr int TSEG = SSEG / KC;          // taps covered by this segment
  static_assert(SSEG % KC == 0, "tap-aligned segments");
  constexpr int MBLK = NWM * 32;
  constexpr int PIX  = NBLK * MBLK;
  constexpr int BSZ  = BN_IN ? CI : 1;
  constexpr int PSM  = FUSE ? NWM : 1;
  constexpr int PSN  = FUSE ? CO * 2 : 1;
  const unsigned short* wkb = (const unsigned short*)wkb_f;

  __shared__ float bscl[BSZ], bshl[BSZ];
  __shared__ float ps[PSM][PSN];

  const int tid  = threadIdx.x;
  const int lane = tid & 63;
  const int wv   = tid >> 6;
  const int wm   = wv / NWN, wn = wv % NWN;
  const int kseg = blockIdx.x / NBLK;
  const int blk  = blockIdx.x % NBLK;
  const int s0   = kseg * SSEG;
  const int tapb = kseg * TSEG;
  const int l15  = lane & 15;
  const int g8   = (lane >> 4) * 8;

  if constexpr (BN_IN) {
    for (int i = tid; i < CI; i += 256) { bscl[i] = bnst[i]; bshl[i] = bnst[CI + i]; }
    __syncthreads();
  }

  // per-lane pixel state: ker values + x base offsets (2 pixels: mt=0,1)
  float kk[2][TSEG];
  int   xo[2];
  int   xt[TSEG];                           // per-tap x offset (pixel-independent)
#pragma unroll
  for (int t = 0; t < TSEG; ++t) {
    int tap = tapb + t;
    xt[t] = ((tap / 3) * HI + (tap % 3)) * CI;
  }
#pragma unroll
  for (int mt = 0; mt < 2; ++mt) {
    int p  = blk * MBLK + wm * 32 + mt * 16 + l15;
    int ow = p % HO, oh = (p / HO) % HO, n = p / (HO * HO);
    const float* gn = g + n * (HI * HI);
    float gc = gn[(oh * 2 + 1) * HI + ow * 2 + 1];
#pragma unroll
    for (int t = 0; t < TSEG; ++t) {
      int tap = tapb + t;
      float d = gn[(oh * 2 + tap / 3) * HI + ow * 2 + (tap % 3)] - gc;
      kk[mt][t] = __expf(-0.5f * d * d);
    }
    xo[mt] = ((n * HI + oh * 2) * HI + ow * 2) * CI;
  }

  f32x4 acc[2][4];
#pragma unroll
  for (int nt = 0; nt < 4; ++nt) {
    float bv = FUSE ? b[wn * 64 + nt * 16 + l15] : 0.0f;
#pragma unroll
    for (int mt = 0; mt < 2; ++mt) acc[mt][nt] = (f32x4){bv, bv, bv, bv};
  }

#pragma unroll
  for (int i = 0; i < SSEG; ++i) {
    const int t  = i / KC;                  // compile-time
    const int kc = i % KC;                  // compile-time
    bf16x8 bfv[4];
#pragma unroll
    for (int nt = 0; nt < 4; ++nt)
      bfv[nt] = *(const bf16x8*)(wkb + ((size_t)(s0 + i) * CO + wn * 64 + nt * 16 + l15) * 32 + g8);
    bf16x8 af[2];
#pragma unroll
    for (int mt = 0; mt < 2; ++mt) {
      const float* ax = x + xo[mt] + xt[t] + kc * 32 + g8;
      float v[8];
      *(float4*)&v[0] = *(const float4*)ax;
      *(float4*)&v[4] = *(const float4*)(ax + 4);
      if constexpr (BN_IN) {
        const int c0 = kc * 32 + g8;
#pragma unroll
        for (int j = 0; j < 8; ++j) v[j] = v[j] * bscl[c0 + j] + bshl[c0 + j];
      }
      const float kv = kk[mt][t];
#pragma unroll
      for (int j = 0; j < 8; ++j) v[j] *= kv;
#pragma unroll
      for (int j = 0; j < 8; ++j) af[mt][j] = (short)f2bf(v[j]);
    }
#pragma unroll
    for (int mt = 0; mt < 2; ++mt)
#pragma unroll
      for (int nt = 0; nt < 4; ++nt)
        acc[mt][nt] = __builtin_amdgcn_mfma_f32_16x16x32_bf16(af[mt], bfv[nt], acc[mt][nt], 0, 0, 0);
  }

  if constexpr (FUSE) {
    // lrelu + store + per-channel (sum, sumsq) partials
#pragma unroll
    for (int nt = 0; nt < 4; ++nt) {
      const int co = wn * 64 + nt * 16 + l15;
      float s = 0.0f, q = 0.0f;
#pragma unroll
      for (int mt = 0; mt < 2; ++mt)
#pragma unroll
        for (int r = 0; r < 4; ++r) {
          float v = acc[mt][nt][r];
          v = v >= 0.0f ? v : NEG_SLOPE * v;
          int p = blk * MBLK + wm * 32 + mt * 16 + ((lane >> 4) << 2) + r;
          y[(size_t)p * CO + co] = v;
          s += v; q += v * v;
        }
      s += __shfl_xor(s, 16, 64); q += __shfl_xor(q, 16, 64);
      s += __shfl_xor(s, 32, 64); q += __shfl_xor(q, 32, 64);
      if (l15 == lane) { ps[wm][co * 2 + 0] = s; ps[wm][co * 2 + 1] = q; }
    }
    __syncthreads();
    if (tid < CO) {
      float s = 0.0f, q = 0.0f;
#pragma unroll
      for (int wmx = 0; wmx < NWM; ++wmx) { s += ps[wmx][tid * 2]; q += ps[wmx][tid * 2 + 1]; }
      part[(tid * NBLK + blk) * 2 + 0] = s;
      part[(tid * NBLK + blk) * 2 + 1] = q;
    }
  } else {
#pragma unroll
    for (int nt = 0; nt < 4; ++nt) {
      const int co = wn * 64 + nt * 16 + l15;
#pragma unroll
      for (int mt = 0; mt < 2; ++mt)
#pragma unroll
        for (int r = 0; r < 4; ++r) {
          int p = blk * MBLK + wm * 32 + mt * 16 + ((lane >> 4) << 2) + r;
          y[((size_t)kseg * PIX + p) * CO + co] = acc[mt][nt][r];
        }
    }
  }
}

// sum NSEG K-partials + bias -> lrelu -> y, plus per-channel BN-stat partials
template <int CO, int EPT, int NSEG>
__global__ void combine_kernel(const float* __restrict__ pout, int pixco,
                               const float* __restrict__ b,
                               float* __restrict__ y, float* __restrict__ part, int NB) {
  const int tid = threadIdx.x, blk = blockIdx.x;
  const int base = blk * (256 * EPT);
  const int co = tid & (CO - 1);
  const float bias = b[co];
  float s = 0.0f, q = 0.0f;
#pragma unroll
  for (int i = 0; i < EPT; ++i) {
    int e = base + i * 256 + tid;
    float v = bias;
#pragma unroll
    for (int sg = 0; sg < NSEG; ++sg) v += pout[(size_t)sg * pixco + e];
    v = v >= 0.0f ? v : NEG_SLOPE * v;
    y[e] = v;
    s += v; q += v * v;
  }
  part[(co * NB + blk) * 2 + 0] = s;
  part[(co * NB + blk) * 2 + 1] = q;
}

// reduce partials -> st = [sc[C]; sh[C]]
template <int C>
__global__ void bnstat2_kernel(const float* __restrict__ part,
                               const float* __restrict__ gamma,
                               const float* __restrict__ beta,
                               float* __restrict__ st, float invM, int NBLK) {
  int c = blockIdx.x;
  int t = threadIdx.x;
  float s = 0.0f, q = 0.0f;
  for (int slot = t; slot < NBLK; slot += 256) {
    s += part[(c * NBLK + slot) * 2 + 0];
    q += part[(c * NBLK + slot) * 2 + 1];
  }
  __shared__ float ss[256], sq[256];
  ss[t] = s; sq[t] = q; __syncthreads();
  for (int off = 128; off > 0; off >>= 1) {
    if (t < off) { ss[t] += ss[t + off]; sq[t] += sq[t + off]; }
    __syncthreads();
  }
  if (t == 0) {
    float m = ss[0] * invM;
    float v = sq[0] * invM - m * m;
    float sc = gamma[c] * rsqrtf(v + EPSBN);
    st[c] = sc;
    st[C + c] = beta[c] - m * sc;
  }
}

// EqualLinear with fused BN4 on input
__global__ void linear_kernel(const float* __restrict__ y4, const float* __restrict__ st4,
                              const float* __restrict__ wadvr, const float* __restrict__ badv,
                              float* __restrict__ out) {
  int n = blockIdx.x, t = threadIdx.x;
  float sc = st4[t], sh = st4[256 + t];
  float s = 0.0f;
  for (int j = t; j < 9216; j += 256) s += (y4[n * 9216 + j] * sc + sh) * wadvr[j];
  __shared__ float ss[256];
  ss[t] = s; __syncthreads();
  for (int off = 128; off > 0; off >>= 1) {
    if (t < off) ss[t] += ss[t + off];
    __syncthreads();
  }
  if (t == 0) out[n] = ss[0] + badv[0];
}

extern "C" void kernel_launch(void* const* d_in, const int* in_sizes, int n_in,
                              void* d_out, int out_size, void* d_ws, size_t ws_size,
                              hipStream_t stream) {
  const float* x    = (const float*)d_in[0];
  const float* gd   = (const float*)d_in[1];
  const float* w1   = (const float*)d_in[2];
  const float* b1   = (const float*)d_in[3];
  const float* w2   = (const float*)d_in[4];
  const float* b2   = (const float*)d_in[5];
  const float* w3   = (const float*)d_in[6];
  const float* b3   = (const float*)d_in[7];
  const float* w4   = (const float*)d_in[8];
  const float* b4   = (const float*)d_in[9];
  const float* bg2  = (const float*)d_in[10];
  const float* bb2  = (const float*)d_in[11];
  const float* bg3  = (const float*)d_in[12];
  const float* bb3  = (const float*)d_in[13];
  const float* bg4  = (const float*)d_in[14];
  const float* bb4  = (const float*)d_in[15];
  const float* wadv = (const float*)d_in[16];
  const float* badv = (const float*)d_in[17];
  float* out = (float*)d_out;
  float* ws  = (float*)d_ws;

  float* st2 = ws + O_STATS;        // [sc64; sh64]
  float* st3 = ws + O_STATS + 128;  // [sc128; sh128]
  float* st4 = ws + O_STATS + 384;  // [sc256; sh256]

  repack_kernel<<<1550, 256, 0, stream>>>(w1, w2, w3, w4, wadv, ws);
  conv1_kernel<<<7552, 256, 0, stream>>>(x, ws + O_W1R, b1, ws + O_Y1);
  avgpool_kernel<<<1741, 256, 0, stream>>>(gd, ws + O_G1, 120, 59, 445568);

  // pac2: CI=32 CO=64, MBLK=128 (4 waves M), fused, 841 blocks
  pac_kernel<32, 64, 59, 29, 4, 1, false, true, 9, 841, 3>
      <<<841, 256, 0, stream>>>(ws + O_Y1, ws + O_G1, ws + O_WKB2, b2, nullptr,
                                ws + O_Y2, ws + O_PART);
  bnstat2_kernel<64><<<64, 256, 0, stream>>>(ws + O_PART, bg2, bb2, st2, 1.0f / 107648.0f, 841);
  avgpool_kernel<<<421, 256, 0, stream>>>(ws + O_G1, ws + O_G2, 59, 29, 107648);

  // pac3: CI=64 CO=128, MBLK=64 (2x2 waves), fused, 392 blocks
  pac_kernel<64, 128, 29, 14, 2, 2, true, true, 18, 392, 2>
      <<<392, 256, 0, stream>>>(ws + O_Y2, ws + O_G2, ws + O_WKB3, b3, st2,
                                ws + O_Y3, ws + O_PART);
  bnstat2_kernel<128><<<128, 256, 0, stream>>>(ws + O_PART, bg3, bb3, st3, 1.0f / 25088.0f, 392);
  avgpool_kernel<<<98, 256, 0, stream>>>(ws + O_G2, ws + O_G3, 29, 14, 25088);

  // pac4: CI=128 CO=256, MBLK=32 (1x4 waves), K-split 3 (SSEG=12): 144x3 = 432 blocks
  pac_kernel<128, 256, 14, 6, 1, 4, true, false, 12, 144, 2>
      <<<432, 256, 0, stream>>>(ws + O_Y3, ws + O_G3, ws + O_WKB4, nullptr, st3,
                                ws + O_POUT4, nullptr);
  combine_kernel<256, 8, 3><<<576, 256, 0, stream>>>(ws + O_POUT4, 1179648, b4,
                                                     ws + O_Y4, ws + O_PART4, 576);
  bnstat2_kernel<256><<<256, 256, 0, stream>>>(ws + O_PART4, bg4, bb4, st4, 1.0f / 4608.0f, 576);

  linear_kernel<<<128, 256, 0, stream>>>(ws + O_Y4, st4, ws + O_WADVR, badv, out);
}

// Round 8
// 105.380 us; speedup vs baseline: 8.5972x; 1.3529x over previous
//
#include <hip/hip_runtime.h>
#include <hip/hip_bf16.h>

#define EPSBN 1e-5f
#define NEG_SLOPE 0.2f

using f32x4  = __attribute__((ext_vector_type(4))) float;
using bf16x8 = __attribute__((ext_vector_type(8))) short;

// ---- workspace layout (float offsets) ----
#define O_Y1B     0            // 128*59*59*32 ushorts = 7,129,088 f (dead after pac2)
#define O_G1      7129088      // 445,568 f32
#define O_Y2B     7574656      // 6,889,472 ushorts = 3,444,736 f (dead after pac3)
#define O_G2      11019392     // 107,648
#define O_WKB2    11127040     // 18,432 ushorts = 9,216 f
#define O_WKB3    11136256     // 73,728 ushorts = 36,864 f
#define O_WKB4    11173120     // 294,912 ushorts = 147,456 f
#define O_WADVR   11320576     // 9,216 f32
#define O_ACC     11329792     // 7,168: acc2[8][64][2] acc3[8][128][2] acc4[8][256][2]
#define O_G3      11336960     // 25,088
#define O_Y3B     11362048     // 3,211,264 ushorts = 1,605,632 f
#define O_POUT4   12967680     // 3*1,179,648 = 3,538,944 f32
#define O_Y4      16506624     // 1,179,648 f32
// total 17,686,272 floats = 70.7 MB
#define A_ACC2    0
#define A_ACC3    1024
#define A_ACC4    3072

__device__ __forceinline__ unsigned short f2bf(float f) {
  union { float f; unsigned int u; } v; v.f = f;
  unsigned int u = v.u + 0x7FFF + ((v.u >> 16) & 1);   // RN-even
  return (unsigned short)(u >> 16);
}
__device__ __forceinline__ float bf2f(unsigned short u) {
  union { unsigned int i; float f; } x; x.i = (unsigned int)u << 16; return x.f;
}

// K1: conv1 + avgpool1 + weight repack + zero stat accumulators (independent work)
#define CONV1_B 7552
#define AVG1_B  1741
#define RPK_B   1548
#define ZERO_B  7
__global__ __launch_bounds__(256) void prep_kernel(
    const float* __restrict__ x, const float* __restrict__ gd,
    const float* __restrict__ w1, const float* __restrict__ b1,
    const float* __restrict__ w2, const float* __restrict__ w3,
    const float* __restrict__ w4, const float* __restrict__ wadv,
    float* __restrict__ ws) {
  const int bi = blockIdx.x, tid = threadIdx.x;
  __shared__ float xs[360];
  __shared__ float wsm[320];
  if (bi < CONV1_B) {                       // ---- conv1 + lrelu -> y1 bf16 NHWC
    const int n = bi / 59, oh = bi % 59;
    for (int i = tid; i < 320; i += 256)
      wsm[i] = (i < 288) ? w1[(i & 31) * 9 + (i >> 5)] : b1[i - 288];
    const float* src = x + ((size_t)n * 120 + oh * 2) * 120;
    for (int i = tid; i < 360; i += 256) xs[i] = src[i];
    __syncthreads();
    const int co = tid & 31;
    const int ow0 = (tid >> 5) * 8;
    float w[9];
#pragma unroll
    for (int k = 0; k < 9; ++k) w[k] = wsm[k * 32 + co];
    const float bias = wsm[288 + co];
    unsigned short* yb = (unsigned short*)(ws + O_Y1B) + (size_t)(n * 59 + oh) * 59 * 32;
#pragma unroll
    for (int j = 0; j < 8; ++j) {
      int ow = ow0 + j;
      if (ow < 59) {
        float acc = bias;
#pragma unroll
        for (int kh = 0; kh < 3; ++kh)
#pragma unroll
          for (int kw = 0; kw < 3; ++kw)
            acc += xs[kh * 120 + ow * 2 + kw] * w[kh * 3 + kw];
        acc = acc >= 0.0f ? acc : NEG_SLOPE * acc;
        yb[ow * 32 + co] = f2bf(acc);
      }
    }
  } else if (bi < CONV1_B + AVG1_B) {       // ---- avgpool gd (120) -> g1 (59)
    int idx = (bi - CONV1_B) * 256 + tid;
    if (idx < 445568) {
      int ow = idx % 59; int t = idx / 59; int oh = t % 59; int n = t / 59;
      const float* gb = gd + (n * 120 + oh * 2) * 120 + ow * 2;
      float s = 0.0f;
#pragma unroll
      for (int kh = 0; kh < 3; ++kh)
#pragma unroll
        for (int kw = 0; kw < 3; ++kw) s += gb[kh * 120 + kw];
      ws[O_G1 + idx] = s * (1.0f / 9.0f);
    }
  } else if (bi < CONV1_B + AVG1_B + RPK_B) {  // ---- weight repack -> bf16 [s][co][k]
    int idx = (bi - CONV1_B - AVG1_B) * 256 + tid;
    if (idx < 18432) {
      int kk = idx & 31; int t = idx >> 5; int co = t & 63; int tap = t >> 6;
      ((unsigned short*)(ws + O_WKB2))[idx] = f2bf(w2[(co * 32 + kk) * 9 + tap]);
    } else if (idx < 92160) {
      int i = idx - 18432;
      int kk = i & 31; int t = i >> 5; int co = t & 127; int t3 = t >> 7;
      int kc = t3 & 1; int tap = t3 >> 1;
      ((unsigned short*)(ws + O_WKB3))[i] = f2bf(w3[(co * 64 + kc * 32 + kk) * 9 + tap]);
    } else if (idx < 387072) {
      int i = idx - 92160;
      int kk = i & 31; int t = i >> 5; int co = t & 255; int t3 = t >> 8;
      int kc = t3 & 3; int tap = t3 >> 2;
      ((unsigned short*)(ws + O_WKB4))[i] = f2bf(w4[(co * 128 + kc * 32 + kk) * 9 + tap]);
    } else if (idx < 396288) {
      int i = idx - 387072;
      int c = i & 255; int hw = i >> 8;
      ws[O_WADVR + i] = wadv[c * 36 + hw] * (1.0f / 96.0f);
    }
  } else {                                  // ---- zero accumulators
    int idx = (bi - CONV1_B - AVG1_B - RPK_B) * 256 + tid;
    if (idx * 4 < 7168) {
      float4 z = {0.0f, 0.0f, 0.0f, 0.0f};
      *reinterpret_cast<float4*>(ws + O_ACC + idx * 4) = z;
    }
  }
}

// Barrier-free MFMA PacConv (R6-verified fragment layouts), bf16 activations.
// BN_IN: prologue computes scale/shift from 8-slot atomic accumulators.
// FUSE: bias+lrelu+bf16 store+atomic BN-stat partials. !FUSE: f32 partial to pout.
// POOL: extra trailing blocks run a 3x3/2 avgpool (independent work).
template <int CI, int CO, int HI, int HO, int NWM, int NWN, bool BN_IN,
          bool FUSE, int SSEG, int NBLK, int MINW, bool POOL>
__global__ __launch_bounds__(256, MINW)
void pac_kernel(const unsigned short* __restrict__ xb, const float* __restrict__ g,
                const float* __restrict__ wkb_f, const float* __restrict__ b,
                const float* __restrict__ gamma, const float* __restrict__ beta,
                const float* __restrict__ accin, float invM,
                unsigned short* __restrict__ yb, float* __restrict__ pout,
                float* __restrict__ accout,
                const float* __restrict__ pin, float* __restrict__ pgout,
                int PHI, int PHO, int PTOT) {
  constexpr int KC   = CI / 32;
  constexpr int NSEG = (9 * KC) / SSEG;
  constexpr int TSEG = SSEG / KC;
  static_assert(SSEG % KC == 0, "tap-aligned segments");
  constexpr int MBLK = NWM * 32;
  constexpr int PIX  = NBLK * MBLK;
  constexpr int BSZ  = BN_IN ? CI : 1;
  constexpr int PSM  = FUSE ? NWM : 1;
  constexpr int PSN  = FUSE ? CO * 2 : 1;
  const unsigned short* wkb = (const unsigned short*)wkb_f;

  const int tid  = threadIdx.x;
  const int bi   = blockIdx.x;

  if constexpr (POOL) {
    if (bi >= NBLK * NSEG) {                 // ---- fused avgpool
      int idx = (bi - NBLK * NSEG) * 256 + tid;
      if (idx < PTOT) {
        int ow = idx % PHO; int t = idx / PHO; int oh = t % PHO; int n = t / PHO;
        const float* gb = pin + (n * PHI + oh * 2) * PHI + ow * 2;
        float s = 0.0f;
#pragma unroll
        for (int kh = 0; kh < 3; ++kh)
#pragma unroll
          for (int kw = 0; kw < 3; ++kw) s += gb[kh * PHI + kw];
        pgout[idx] = s * (1.0f / 9.0f);
      }
      return;
    }
  }

  __shared__ float bscl[BSZ], bshl[BSZ];
  __shared__ float ps[PSM][PSN];

  const int lane = tid & 63;
  const int wv   = tid >> 6;
  const int wm   = wv / NWN, wn = wv % NWN;
  const int kseg = bi / NBLK;
  const int blk  = bi % NBLK;
  const int s0   = kseg * SSEG;
  const int tapb = kseg * TSEG;
  const int l15  = lane & 15;
  const int g8   = (lane >> 4) * 8;

  if constexpr (BN_IN) {                     // stats from 8-slot accumulators
    if (tid < CI) {
      float s = 0.0f, q = 0.0f;
#pragma unroll
      for (int sl = 0; sl < 8; ++sl) {
        s += accin[(sl * CI + tid) * 2 + 0];
        q += accin[(sl * CI + tid) * 2 + 1];
      }
      float m = s * invM;
      float var = q * invM - m * m;
      float sc = gamma[tid] * rsqrtf(var + EPSBN);
      bscl[tid] = sc;
      bshl[tid] = beta[tid] - m * sc;
    }
    __syncthreads();
  }

  float kk[2][TSEG];
  int   xo[2];
  int   xt[TSEG];
#pragma unroll
  for (int t = 0; t < TSEG; ++t) {
    int tap = tapb + t;
    xt[t] = ((tap / 3) * HI + (tap % 3)) * CI;
  }
#pragma unroll
  for (int mt = 0; mt < 2; ++mt) {
    int p  = blk * MBLK + wm * 32 + mt * 16 + l15;
    int ow = p % HO, oh = (p / HO) % HO, n = p / (HO * HO);
    const float* gn = g + n * (HI * HI);
    float gc = gn[(oh * 2 + 1) * HI + ow * 2 + 1];
#pragma unroll
    for (int t = 0; t < TSEG; ++t) {
      int tap = tapb + t;
      float d = gn[(oh * 2 + tap / 3) * HI + ow * 2 + (tap % 3)] - gc;
      kk[mt][t] = __expf(-0.5f * d * d);
    }
    xo[mt] = ((n * HI + oh * 2) * HI + ow * 2) * CI;
  }

  f32x4 acc[2][4];
#pragma unroll
  for (int nt = 0; nt < 4; ++nt) {
    float bv = FUSE ? b[wn * 64 + nt * 16 + l15] : 0.0f;
#pragma unroll
    for (int mt = 0; mt < 2; ++mt) acc[mt][nt] = (f32x4){bv, bv, bv, bv};
  }

#pragma unroll
  for (int i = 0; i < SSEG; ++i) {
    const int t  = i / KC;
    const int kc = i % KC;
    bf16x8 bfv[4];
#pragma unroll
    for (int nt = 0; nt < 4; ++nt)
      bfv[nt] = *(const bf16x8*)(wkb + ((size_t)(s0 + i) * CO + wn * 64 + nt * 16 + l15) * 32 + g8);
    bf16x8 af[2];
#pragma unroll
    for (int mt = 0; mt < 2; ++mt) {
      const unsigned short* ax = xb + xo[mt] + xt[t] + kc * 32 + g8;
      bf16x8 u = *(const bf16x8*)ax;
      float v[8];
#pragma unroll
      for (int j = 0; j < 8; ++j) v[j] = bf2f((unsigned short)u[j]);
      if constexpr (BN_IN) {
        const int c0 = kc * 32 + g8;
#pragma unroll
        for (int j = 0; j < 8; ++j) v[j] = v[j] * bscl[c0 + j] + bshl[c0 + j];
      }
      const float kv = kk[mt][t];
#pragma unroll
      for (int j = 0; j < 8; ++j) v[j] *= kv;
#pragma unroll
      for (int j = 0; j < 8; ++j) af[mt][j] = (short)f2bf(v[j]);
    }
#pragma unroll
    for (int mt = 0; mt < 2; ++mt)
#pragma unroll
      for (int nt = 0; nt < 4; ++nt)
        acc[mt][nt] = __builtin_amdgcn_mfma_f32_16x16x32_bf16(af[mt], bfv[nt], acc[mt][nt], 0, 0, 0);
  }

  if constexpr (FUSE) {
#pragma unroll
    for (int nt = 0; nt < 4; ++nt) {
      const int co = wn * 64 + nt * 16 + l15;
      float s = 0.0f, q = 0.0f;
#pragma unroll
      for (int mt = 0; mt < 2; ++mt)
#pragma unroll
        for (int r = 0; r < 4; ++r) {
          float v = acc[mt][nt][r];
          v = v >= 0.0f ? v : NEG_SLOPE * v;
          int p = blk * MBLK + wm * 32 + mt * 16 + ((lane >> 4) << 2) + r;
          yb[(size_t)p * CO + co] = f2bf(v);
          s += v; q += v * v;
        }
      s += __shfl_xor(s, 16, 64); q += __shfl_xor(q, 16, 64);
      s += __shfl_xor(s, 32, 64); q += __shfl_xor(q, 32, 64);
      if (l15 == lane) { ps[wm][co * 2 + 0] = s; ps[wm][co * 2 + 1] = q; }
    }
    __syncthreads();
    if (tid < CO) {
      float s = 0.0f, q = 0.0f;
#pragma unroll
      for (int wmx = 0; wmx < NWM; ++wmx) { s += ps[wmx][tid * 2]; q += ps[wmx][tid * 2 + 1]; }
      atomicAdd(&accout[((blk & 7) * CO + tid) * 2 + 0], s);
      atomicAdd(&accout[((blk & 7) * CO + tid) * 2 + 1], q);
    }
  } else {
#pragma unroll
    for (int nt = 0; nt < 4; ++nt) {
      const int co = wn * 64 + nt * 16 + l15;
#pragma unroll
      for (int mt = 0; mt < 2; ++mt)
#pragma unroll
        for (int r = 0; r < 4; ++r) {
          int p = blk * MBLK + wm * 32 + mt * 16 + ((lane >> 4) << 2) + r;
          pout[((size_t)kseg * PIX + p) * CO + co] = acc[mt][nt][r];
        }
    }
  }
}

// sum NSEG K-partials + bias -> lrelu -> y4 f32, atomic BN-stat partials
template <int CO, int EPT, int NSEG>
__global__ void combine_kernel(const float* __restrict__ pout, int pixco,
                               const float* __restrict__ b,
                               float* __restrict__ y, float* __restrict__ acc) {
  const int tid = threadIdx.x, blk = blockIdx.x;
  const int base = blk * (256 * EPT);
  const int co = tid & (CO - 1);
  const float bias = b[co];
  float s = 0.0f, q = 0.0f;
#pragma unroll
  for (int i = 0; i < EPT; ++i) {
    int e = base + i * 256 + tid;
    float v = bias;
#pragma unroll
    for (int sg = 0; sg < NSEG; ++sg) v += pout[(size_t)sg * pixco + e];
    v = v >= 0.0f ? v : NEG_SLOPE * v;
    y[e] = v;
    s += v; q += v * v;
  }
  atomicAdd(&acc[((blk & 7) * CO + co) * 2 + 0], s);
  atomicAdd(&acc[((blk & 7) * CO + co) * 2 + 1], q);
}

// EqualLinear; per-thread BN4 scale/shift computed from accumulators
__global__ void linear_kernel(const float* __restrict__ y4, const float* __restrict__ acc4,
                              const float* __restrict__ bg4, const float* __restrict__ bb4,
                              const float* __restrict__ wadvr, const float* __restrict__ badv,
                              float* __restrict__ out) {
  int n = blockIdx.x, t = threadIdx.x;
  float s0 = 0.0f, q0 = 0.0f;
#pragma unroll
  for (int sl = 0; sl < 8; ++sl) {
    s0 += acc4[(sl * 256 + t) * 2 + 0];
    q0 += acc4[(sl * 256 + t) * 2 + 1];
  }
  float m = s0 * (1.0f / 4608.0f);
  float var = q0 * (1.0f / 4608.0f) - m * m;
  float sc = bg4[t] * rsqrtf(var + EPSBN);
  float sh = bb4[t] - m * sc;
  float s = 0.0f;
  for (int j = t; j < 9216; j += 256) s += (y4[n * 9216 + j] * sc + sh) * wadvr[j];
  __shared__ float ss[256];
  ss[t] = s; __syncthreads();
  for (int off = 128; off > 0; off >>= 1) {
    if (t < off) ss[t] += ss[t + off];
    __syncthreads();
  }
  if (t == 0) out[n] = ss[0] + badv[0];
}

extern "C" void kernel_launch(void* const* d_in, const int* in_sizes, int n_in,
                              void* d_out, int out_size, void* d_ws, size_t ws_size,
                              hipStream_t stream) {
  const float* x    = (const float*)d_in[0];
  const float* gd   = (const float*)d_in[1];
  const float* w1   = (const float*)d_in[2];
  const float* b1   = (const float*)d_in[3];
  const float* w2   = (const float*)d_in[4];
  const float* b2   = (const float*)d_in[5];
  const float* w3   = (const float*)d_in[6];
  const float* b3   = (const float*)d_in[7];
  const float* w4   = (const float*)d_in[8];
  const float* b4   = (const float*)d_in[9];
  const float* bg2  = (const float*)d_in[10];
  const float* bb2  = (const float*)d_in[11];
  const float* bg3  = (const float*)d_in[12];
  const float* bb3  = (const float*)d_in[13];
  const float* bg4  = (const float*)d_in[14];
  const float* bb4  = (const float*)d_in[15];
  const float* wadv = (const float*)d_in[16];
  const float* badv = (const float*)d_in[17];
  float* out = (float*)d_out;
  float* ws  = (float*)d_ws;

  unsigned short* y1b = (unsigned short*)(ws + O_Y1B);
  unsigned short* y2b = (unsigned short*)(ws + O_Y2B);
  unsigned short* y3b = (unsigned short*)(ws + O_Y3B);
  float* acc2 = ws + O_ACC + A_ACC2;
  float* acc3 = ws + O_ACC + A_ACC3;
  float* acc4 = ws + O_ACC + A_ACC4;

  // K1: conv1 + avgpool1 + repack + zero accumulators
  prep_kernel<<<CONV1_B + AVG1_B + RPK_B + ZERO_B, 256, 0, stream>>>(
      x, gd, w1, b1, w2, w3, w4, wadv, ws);

  // K2: pac2 (841 blocks) + avgpool g1->g2 (421 blocks)
  pac_kernel<32, 64, 59, 29, 4, 1, false, true, 9, 841, 3, true>
      <<<1262, 256, 0, stream>>>(y1b, ws + O_G1, ws + O_WKB2, b2,
                                 nullptr, nullptr, nullptr, 0.0f,
                                 y2b, nullptr, acc2,
                                 ws + O_G1, ws + O_G2, 59, 29, 107648);

  // K3: pac3 (392 blocks, BN2 from acc2) + avgpool g2->g3 (98 blocks)
  pac_kernel<64, 128, 29, 14, 2, 2, true, true, 18, 392, 2, true>
      <<<490, 256, 0, stream>>>(y2b, ws + O_G2, ws + O_WKB3, b3,
                                bg2, bb2, acc2, 1.0f / 107648.0f,
                                y3b, nullptr, acc3,
                                ws + O_G2, ws + O_G3, 29, 14, 25088);

  // K4: pac4, K-split 3 (BN3 from acc3) -> raw partials
  pac_kernel<128, 256, 14, 6, 1, 4, true, false, 12, 144, 2, false>
      <<<432, 256, 0, stream>>>(y3b, ws + O_G3, ws + O_WKB4, nullptr,
                                bg3, bb3, acc3, 1.0f / 25088.0f,
                                nullptr, ws + O_POUT4, nullptr,
                                nullptr, nullptr, 0, 0, 0);

  // K5: combine partials + bias + lrelu -> y4, atomic BN4 stats
  combine_kernel<256, 8, 3><<<576, 256, 0, stream>>>(ws + O_POUT4, 1179648, b4,
                                                     ws + O_Y4, acc4);

  // K6: EqualLinear with in-prologue BN4 stats
  linear_kernel<<<128, 256, 0, stream>>>(ws + O_Y4, acc4, bg4, bb4,
                                         ws + O_WADVR, badv, out);
}